// Round 1
// baseline (39.530 us; speedup 1.0000x reference)
//
#include <hip/hip_runtime.h>
#include <math.h>

// LightconvLayer: x (T,B,C) f32, weight (H,K) f32 -> out (T,B,C) f32
// out[t,b,c] = sum_k softmax(weight[c/(C/H)])[k] * x[t+k-PAD_L, b, c] (zero-pad left)
#define T_LEN 2048
#define B_SZ  8
#define C_SZ  1024
#define NH    16
#define KW    31
#define PADL  30
#define TT    32      // outputs per thread along t
#define BLOCK 256     // 4 waves; each wave = exactly one head (64 channels)

__global__ __launch_bounds__(BLOCK) void lightconv_kernel(
    const float* __restrict__ x, const float* __restrict__ weight,
    float* __restrict__ out) {
  __shared__ float sw[NH][KW];
  const int tid = threadIdx.x;

  // --- softmax(weight) into LDS: 16 threads, one head each ---
  if (tid < NH) {
    float wv[KW];
    float m = -1e30f;
#pragma unroll
    for (int k = 0; k < KW; ++k) {
      wv[k] = weight[tid * KW + k];
      m = fmaxf(m, wv[k]);
    }
    float s = 0.f;
#pragma unroll
    for (int k = 0; k < KW; ++k) {
      wv[k] = expf(wv[k] - m);
      s += wv[k];
    }
    const float inv = 1.f / s;
#pragma unroll
    for (int k = 0; k < KW; ++k) sw[tid][k] = wv[k] * inv;
  }
  __syncthreads();

  const int c  = blockIdx.z * BLOCK + tid;   // channel (lane-contiguous -> coalesced)
  const int b  = blockIdx.y;                 // batch
  const int t0 = blockIdx.x * TT;            // t-strip base

  // head is wave-uniform (64 channels/head, waves 64-aligned) -> hoist taps to SGPRs
  const int head = __builtin_amdgcn_readfirstlane(c >> 6);
  float wk[KW];
#pragma unroll
  for (int k = 0; k < KW; ++k) {
    wk[k] = __uint_as_float(
        __builtin_amdgcn_readfirstlane(__float_as_uint(sw[head][k])));
  }

  // load TT+KW-1 inputs along t into registers (compile-time indices only)
  const float* xp = x + (size_t)b * C_SZ + c;
  float xv[TT + KW - 1];
#pragma unroll
  for (int i = 0; i < TT + KW - 1; ++i) {
    const int t = t0 + i - PADL;  // block-uniform condition; only first t-strip clips
    xv[i] = (t >= 0) ? xp[(size_t)t * (B_SZ * C_SZ)] : 0.f;
  }

  float* op = out + ((size_t)t0 * B_SZ + b) * C_SZ + c;
#pragma unroll
  for (int o = 0; o < TT; ++o) {
    float acc = 0.f;
#pragma unroll
    for (int k = 0; k < KW; ++k) acc = fmaf(wk[k], xv[o + k], acc);
    op[(size_t)o * (B_SZ * C_SZ)] = acc;
  }
}

extern "C" void kernel_launch(void* const* d_in, const int* in_sizes, int n_in,
                              void* d_out, int out_size, void* d_ws, size_t ws_size,
                              hipStream_t stream) {
  const float* x = (const float*)d_in[0];      // (T,B,C) f32
  const float* w = (const float*)d_in[1];      // (H,K) f32
  float* out = (float*)d_out;                  // (T,B,C) f32
  (void)in_sizes; (void)n_in; (void)out_size; (void)d_ws; (void)ws_size;

  dim3 grid(T_LEN / TT, B_SZ, C_SZ / BLOCK);   // (64, 8, 4)
  dim3 block(BLOCK);
  lightconv_kernel<<<grid, block, 0, stream>>>(x, w, out);
}